// Round 5
// baseline (190.996 us; speedup 1.0000x reference)
//
#include <hip/hip_runtime.h>

// Round 10: K=2 batches per lane — attack the real wall: LDS READ BANDWIDTH.
// Model fit across r6/r8/r9: LDS reads are charged per-lane even when 16
// lanes broadcast the same address. All three rounds read 512 B of weights
// per batch per site-step -> 6.55 GB of LDS reads/dispatch -> ~83 us floor
// at ~122 B/cy/CU. r9's 88 us == that floor (VALUBusy only 47%).
// Now each lane carries v for 2 batches (bl0=g, bl1=g+16): one weight
// ds_read_b128 feeds both -> 256 B/batch-step -> ~44 us LDS floor, while
// wave-normalized VALU stays 1.5 instr/batch-step (floor ~31 us).
// Cost: 1024 waves total = 1 wave/SIMD. Latency covered by (a) explicit
// register double-buffer of site weights (prefetch j+1 during compute j;
// 192 cy compute >> ~120 cy LDS latency), (b) 128-thr blocks, grid 512 =
// 2 independent barrier groups per CU overlapping each other's staging,
// (c) T14 async staging. r9's verified scatter layout / op_sel site_step /
// combine are reused verbatim; only the batch mapping changed.

#define NSITES 784
#define DIM    8
#define ODIM   10
#define LABEL  392
#define WSITE  144   // floats per staged site: 4 q-columns * 36
#define QST    36    // column stride: 32 + 4 pad -> column q at banks 4q..4q+3
#define XST    20    // xb row stride: 16 sites + 4 pad

typedef float v2f __attribute__((ext_vector_type(2)));

// quad_perm rotations (each 4-lane quad = one batch's 4 output-pair lanes)
__device__ __forceinline__ float dpp_q1(float s){float d;asm("v_mov_b32_dpp %0, %1 quad_perm:[1,0,3,2] row_mask:0xf bank_mask:0xf":"=v"(d):"v"(s));return d;}
__device__ __forceinline__ float dpp_q2(float s){float d;asm("v_mov_b32_dpp %0, %1 quad_perm:[2,3,0,1] row_mask:0xf bank_mask:0xf":"=v"(d):"v"(s));return d;}
__device__ __forceinline__ float dpp_q3(float s){float d;asm("v_mov_b32_dpp %0, %1 quad_perm:[3,2,1,0] row_mask:0xf bank_mask:0xf":"=v"(d):"v"(s));return d;}

__device__ __forceinline__ v2f pk_mul(v2f a, v2f b){v2f d;asm("v_pk_mul_f32 %0,%1,%2":"=v"(d):"v"(a),"v"(b));return d;}
__device__ __forceinline__ v2f pk_fma(v2f a, v2f b, v2f c){v2f d;asm("v_pk_fma_f32 %0,%1,%2,%3":"=v"(d):"v"(a),"v"(b),"v"(c));return d;}
// src0 half-swapped: lo result uses src0.hi, hi result uses src0.lo
__device__ __forceinline__ v2f pk_fma_s(v2f a, v2f b, v2f c){v2f d;asm("v_pk_fma_f32 %0,%1,%2,%3 op_sel:[1,0,0] op_sel_hi:[0,1,1]":"=v"(d):"v"(a),"v"(b),"v"(c));return d;}
// src0 broadcast lo / broadcast hi (for the per-site p blend)
__device__ __forceinline__ v2f pk_fma_blo(v2f a, v2f b, v2f c){v2f d;asm("v_pk_fma_f32 %0,%1,%2,%3 op_sel:[0,0,0] op_sel_hi:[0,1,1]":"=v"(d):"v"(a),"v"(b),"v"(c));return d;}
__device__ __forceinline__ v2f pk_fma_bhi(v2f a, v2f b, v2f c){v2f d;asm("v_pk_fma_f32 %0,%1,%2,%3 op_sel:[1,0,0] op_sel_hi:[1,1,1]":"=v"(d):"v"(a),"v"(b),"v"(c));return d;}
// a - b
__device__ __forceinline__ v2f pk_sub(v2f a, v2f b){v2f d;asm("v_pk_add_f32 %0,%1,%2 neg_lo:[0,1] neg_hi:[0,1]":"=v"(d):"v"(a),"v"(b));return d;}

__device__ __forceinline__ v2f XY(const float4& q){ v2f r = {q.x, q.y}; return r; }
__device__ __forceinline__ v2f ZW(const float4& q){ v2f r = {q.z, q.w}; return r; }

// One MPS site for one batch, output pair (2q,2q+1) per lane.
// Weights come from registers (r[0..7] = the lane's 32-float column).
template <bool PHI>
__device__ __forceinline__ v2f site_step(v2f v, const float4 (&r)[8], v2f pp) {
    v2f d1; d1.x = dpp_q1(v.x); d1.y = dpp_q1(v.y);   // v[·^2] pairs
    v2f d2; d2.x = dpp_q2(v.x); d2.y = dpp_q2(v.y);   // v[·^4] pairs
    v2f d3; d3.x = dpp_q3(v.x); d3.y = dpp_q3(v.y);   // v[·^6] pairs
    v2f a0 = pk_mul (v,  XY(r[0]));
    a0 = pk_fma_s(v,  ZW(r[0]), a0);
    a0 = pk_fma  (d1, XY(r[1]), a0);
    a0 = pk_fma_s(d1, ZW(r[1]), a0);
    a0 = pk_fma  (d2, XY(r[2]), a0);
    a0 = pk_fma_s(d2, ZW(r[2]), a0);
    a0 = pk_fma  (d3, XY(r[3]), a0);
    a0 = pk_fma_s(d3, ZW(r[3]), a0);
    v2f a1 = pk_mul (v,  XY(r[4]));
    a1 = pk_fma_s(v,  ZW(r[4]), a1);
    a1 = pk_fma  (d1, XY(r[5]), a1);
    a1 = pk_fma_s(d1, ZW(r[5]), a1);
    a1 = pk_fma  (d2, XY(r[6]), a1);
    a1 = pk_fma_s(d2, ZW(r[6]), a1);
    a1 = pk_fma  (d3, XY(r[7]), a1);
    a1 = pk_fma_s(d3, ZW(r[7]), a1);
    const v2f df = pk_sub(a1, a0);
    return PHI ? pk_fma_bhi(pp, df, a0) : pk_fma_blo(pp, df, a0);
}

__global__ __launch_bounds__(128, 1) void mps_fused(
    const float* __restrict__ x,      // [B, N]
    const float* __restrict__ w0,     // [2, D]
    const float* __restrict__ Wl,     // [391, d, f, e]
    const float* __restrict__ wlab,   // [D, 2, D, O] = 1280 floats
    const float* __restrict__ Wr,     // [390, d, f, e]
    const float* __restrict__ wlast,  // [D, 2]
    float* __restrict__ out)          // [B, O]
{
    __shared__ float wb[2][2][16 * WSITE];  // [side][buf] 36.9 KB
    __shared__ float xb[2][2][32 * XST];    // [side][buf] 10.2 KB
    __shared__ float wl[1280];              // 5.1 KB
    __shared__ float vout[2][256];          // 2.0 KB        (54.3 KB total)

    const int tid  = threadIdx.x;
    const int side = tid >> 6;              // wave 0: left, wave 1: right
    const int stid = tid & 63;
    const int q    = stid & 3;              // output-pair index (e = 2q,2q+1)
    const int g    = stid >> 2;             // batch group 0..15
    const int bl0  = g;                     // lane's two block-local batches
    const int bl1  = g + 16;
    const int b0   = blockIdx.x * 32;       // 32 batches per block, grid 512

    for (int k = tid; k < 320; k += 128)
        *(float4*)&wl[k * 4] = *(const float4*)&wlab[k * 4];

    // ------- staging registers (T14: load early, write late) -------
    float4 wr[8];
    float  xr[8];

    auto stage_load = [&](int c, int nt) {
        const float* W = side == 0 ? Wl : Wr;
        #pragma unroll
        for (int r = 0; r < 8; ++r) {
            const int cid = stid + 64 * r;         // 0..511 = 16 sites x 32
            const int s   = cid >> 5;
            const int u   = cid & 31;
            if (s < nt) {
                const int row = side == 0 ? (c * 16 + s) : (389 - c * 16 - s);
                wr[r] = *(const float4*)(W + (size_t)row * 128 + u * 4);
            }
        }
        #pragma unroll
        for (int r = 0; r < 8; ++r) {
            const int cid = stid + 64 * r;         // 0..511 = 32 b x 16 s
            const int b   = cid >> 4;
            const int sx  = cid & 15;
            if (sx < nt) {
                const int col = side == 0 ? (1 + c * 16 + sx) : (782 - c * 16 - sx);
                xr[r] = x[(size_t)(b0 + b) * NSITES + col];
            }
        }
    };

    // scatter (verified r9): left  W[d][f][e] -> [e>>1]*36 + (f*8+(e^d))*2 + (e&1)
    //                        right W[d][f][e] -> [d>>1]*36 + (f*8+(d^e))*2 + (d&1)
    auto stage_write = [&](int bufi, int nt) {
        float* wdst = wb[side][bufi];
        float* xdst = xb[side][bufi];
        #pragma unroll
        for (int r = 0; r < 8; ++r) {
            const int cid = stid + 64 * r;
            const int s   = cid >> 5;
            const int u   = cid & 31;
            const int d   = u >> 2;
            const int f   = (u >> 1) & 1;
            const int e4  = (u & 1) * 4;
            if (s < nt) {
                float* dst = wdst + s * WSITE;
                const float vals[4] = {wr[r].x, wr[r].y, wr[r].z, wr[r].w};
                #pragma unroll
                for (int k = 0; k < 4; ++k) {
                    const int e = e4 + k;
                    if (side == 0)
                        dst[(e >> 1) * QST + (f * 8 + (e ^ d)) * 2 + (e & 1)] = vals[k];
                    else
                        dst[(d >> 1) * QST + (f * 8 + (d ^ e)) * 2 + (d & 1)] = vals[k];
                }
            }
        }
        #pragma unroll
        for (int r = 0; r < 8; ++r) {
            const int cid = stid + 64 * r;
            const int b   = cid >> 4;
            const int sx  = cid & 15;
            if (sx < nt)
                xdst[b * XST + sx] = xr[r];
        }
    };

    // ------- boundary init: output pair (2q,2q+1) for batches bl0, bl1 -------
    v2f vv0, vv1;
    {
        const int e0 = 2 * q, e1 = 2 * q + 1;
        if (side == 0) {
            const float p0 = x[(size_t)(b0 + bl0) * NSITES];
            const float p1 = x[(size_t)(b0 + bl1) * NSITES];
            vv0.x = fmaf(1.0f - p0, w0[e0], p0 * w0[DIM + e0]);
            vv0.y = fmaf(1.0f - p0, w0[e1], p0 * w0[DIM + e1]);
            vv1.x = fmaf(1.0f - p1, w0[e0], p1 * w0[DIM + e0]);
            vv1.y = fmaf(1.0f - p1, w0[e1], p1 * w0[DIM + e1]);
        } else {
            const float p0 = x[(size_t)(b0 + bl0) * NSITES + (NSITES - 1)];
            const float p1 = x[(size_t)(b0 + bl1) * NSITES + (NSITES - 1)];
            vv0.x = fmaf(1.0f - p0, wlast[e0 * 2], p0 * wlast[e0 * 2 + 1]);
            vv0.y = fmaf(1.0f - p0, wlast[e1 * 2], p0 * wlast[e1 * 2 + 1]);
            vv1.x = fmaf(1.0f - p1, wlast[e0 * 2], p1 * wlast[e0 * 2 + 1]);
            vv1.y = fmaf(1.0f - p1, wlast[e1 * 2], p1 * wlast[e1 * 2 + 1]);
        }
    }

    const int nt_tail = side ? 6 : 7;

    stage_load(0, 16);
    stage_write(0, 16);
    int buf = 0;

    // 16 sites, register-double-buffered weights (prefetch j+1 during j).
    auto compute16 = [&](int bufi) {
        const float* wp  = &wb[side][bufi][q * QST];
        const float* xp0 = &xb[side][bufi][bl0 * XST];
        const float* xp1 = &xb[side][bufi][bl1 * XST];
        float4 wg[2][8];
        #pragma unroll
        for (int i = 0; i < 8; ++i)
            wg[0][i] = *(const float4*)(wp + i * 4);
        float4 xqA, xqB;
        #pragma unroll
        for (int j = 0; j < 16; ++j) {          // fully unrolled: static idx
            if ((j & 3) == 0) {
                xqA = *(const float4*)(xp0 + j);
                xqB = *(const float4*)(xp1 + j);
            }
            if (j < 15) {
                #pragma unroll
                for (int i = 0; i < 8; ++i)
                    wg[(j + 1) & 1][i] = *(const float4*)(wp + (j + 1) * WSITE + i * 4);
            }
            const v2f pA = (j & 2) ? ZW(xqA) : XY(xqA);
            const v2f pB = (j & 2) ? ZW(xqB) : XY(xqB);
            if (j & 1) {
                vv0 = site_step<true >(vv0, wg[j & 1], pA);
                vv1 = site_step<true >(vv1, wg[j & 1], pB);
            } else {
                vv0 = site_step<false>(vv0, wg[j & 1], pA);
                vv1 = site_step<false>(vv1, wg[j & 1], pB);
            }
        }
    };

    #pragma unroll 1
    for (int c = 0; c < 23; ++c) {            // chunks 0..22 (full)
        __syncthreads();                      // chunk c staged; buf^1 free
        stage_load(c + 1, 16);
        compute16(buf);
        __builtin_amdgcn_sched_barrier(0);    // keep LDS writes after compute
        stage_write(buf ^ 1, 16);
        buf ^= 1;
    }

    // chunk 23 (full) + prefetch tail chunk 24
    __syncthreads();
    stage_load(24, nt_tail);
    compute16(buf);
    __builtin_amdgcn_sched_barrier(0);
    stage_write(buf ^ 1, nt_tail);
    buf ^= 1;

    // tail chunk 24 (7 sites left / 6 sites right)
    __syncthreads();
    {
        const float* wp  = &wb[side][buf][q * QST];
        const float* xp0 = &xb[side][buf][bl0 * XST];
        const float* xp1 = &xb[side][buf][bl1 * XST];
        for (int j = 0; j < nt_tail; ++j) {
            float4 r[8];
            #pragma unroll
            for (int i = 0; i < 8; ++i)
                r[i] = *(const float4*)(wp + j * WSITE + i * 4);
            v2f pA; pA.x = xp0[j]; pA.y = pA.x;
            v2f pB; pB.x = xp1[j]; pB.y = pB.x;
            vv0 = site_step<false>(vv0, r, pA);
            vv1 = site_step<false>(vv1, r, pB);
        }
    }

    // ------- publish bond vectors and combine at the label site -------
    *(v2f*)&vout[side][bl0 * 8 + 2 * q] = vv0;
    *(v2f*)&vout[side][bl1 * 8 + 2 * q] = vv1;
    __syncthreads();

    for (int idx = tid; idx < 320; idx += 128) {   // 32 batches x 10 outputs
        const int b = idx / 10;
        const int o = idx - b * 10;
        const float p = x[(size_t)(b0 + b) * NSITES + LABEL];
        const float qq = 1.0f - p;
        const float* vl = &vout[0][b * 8];
        const float* rv = &vout[1][b * 8];
        float acc = 0.0f;
        #pragma unroll
        for (int d = 0; d < DIM; ++d) {
            const float vld = vl[d];
            #pragma unroll
            for (int ee = 0; ee < DIM; ++ee) {
                const float m = fmaf(qq, wl[((d * 2 + 0) * DIM + ee) * ODIM + o],
                                     p * wl[((d * 2 + 1) * DIM + ee) * ODIM + o]);
                acc = fmaf(vld * rv[ee], m, acc);
            }
        }
        out[(size_t)(b0 + b) * ODIM + o] = acc;
    }
}

extern "C" void kernel_launch(void* const* d_in, const int* in_sizes, int n_in,
                              void* d_out, int out_size, void* d_ws, size_t ws_size,
                              hipStream_t stream) {
    (void)in_sizes; (void)n_in; (void)d_ws; (void)ws_size; (void)out_size;
    const float* x     = (const float*)d_in[0];
    const float* w0    = (const float*)d_in[1];
    const float* Wl    = (const float*)d_in[2];
    const float* wlab  = (const float*)d_in[3];
    const float* Wr    = (const float*)d_in[4];
    const float* wlast = (const float*)d_in[5];

    mps_fused<<<512, 128, 0, stream>>>(x, w0, Wl, wlab, Wr, wlast, (float*)d_out);
}

// Round 6
// 181.947 us; speedup vs baseline: 1.0497x; 1.0497x over previous
//
#include <hip/hip_runtime.h>

// Round 11: E=1,K=2 — halve LDS traffic vs r9 while KEEPING 2 waves/SIMD.
// Model (fits r6-r10): VALU ~4cy/instr/wave; LDS pipe ~128 B/cy/CU charged
// per lane. r9's 88 us == its LDS floor (512 cy/site/CU); r10's K=2 halved
// LDS but dropped to 1 wave/SIMD and died on in-order serialization (33%
// VALUBusy). Constraint algebra: waves = 4096/(E*K), LDS/batch ~ 1/K.
// -> E=1 (lane owns one output bond e), K=2 (two batches packed in a v2f):
// 2048 waves = 2/SIMD AND K=2. The enabler vs r8 (which duplicated weights):
// VOP3P op_sel broadcasts one 32-bit half of src1 to both packed halves, so
// NON-duplicated weights (4 x ds_read_b128 = 16 floats/site) feed packed
// FMAs directly. Per site/wave: 14 dpp + 16 bcast-pk + sub + blend = 32
// VALU for 16 batches. Per CU-site: LDS 288 cy ~ VALU 288 cy — balanced.
// x staged pair-interleaved: one b128 = (pA,pB) for 2 sites, no packing movs.
// Weight scatter = r6's verified e*20-column XOR layout (32-bank tiling).
// Geometry: 512 blocks x 256 thr (waves 0-1 left / 2-3 right, 32 batches),
// 2 blocks/CU = 2 independent barrier groups, 2 waves/SIMD. T14 staging.

#define NSITES 784
#define DIM    8
#define ODIM   10
#define LABEL  392
#define WSITE  160   // floats per staged site: 8 columns * 20
#define CST    20    // column stride: col e at banks (20e mod 32) -> perfect tiling
#define XPST   34    // x pair-row stride: 16 sites * 2 + 2 pad

typedef float v2f __attribute__((ext_vector_type(2)));

// quad_perm / row_half_mirror rotations (e = lane&7; verified r6/r8/r10)
__device__ __forceinline__ float dpp_q1(float s){float d;asm("v_mov_b32_dpp %0, %1 quad_perm:[1,0,3,2] row_mask:0xf bank_mask:0xf":"=v"(d):"v"(s));return d;}
__device__ __forceinline__ float dpp_q2(float s){float d;asm("v_mov_b32_dpp %0, %1 quad_perm:[2,3,0,1] row_mask:0xf bank_mask:0xf":"=v"(d):"v"(s));return d;}
__device__ __forceinline__ float dpp_q3(float s){float d;asm("v_mov_b32_dpp %0, %1 quad_perm:[3,2,1,0] row_mask:0xf bank_mask:0xf":"=v"(d):"v"(s));return d;}
__device__ __forceinline__ float dpp_x7(float s){float d;asm("v_mov_b32_dpp %0, %1 row_half_mirror row_mask:0xf bank_mask:0xf":"=v"(d):"v"(s));return d;}

// plain packed ops
__device__ __forceinline__ v2f pk_fma(v2f a, v2f b, v2f c){v2f d;asm("v_pk_fma_f32 %0,%1,%2,%3":"=v"(d):"v"(a),"v"(b),"v"(c));return d;}
__device__ __forceinline__ v2f pk_sub(v2f a, v2f b){v2f d;asm("v_pk_add_f32 %0,%1,%2 neg_lo:[0,1] neg_hi:[0,1]":"=v"(d):"v"(a),"v"(b));return d;}
// src1 broadcast: both result halves read the SAME 32-bit half of src1.
// (op_sel[i] = src half for LO result, op_sel_hi[i] = src half for HI result)
__device__ __forceinline__ v2f pk_mul_blo(v2f a, v2f b){v2f d;asm("v_pk_mul_f32 %0,%1,%2 op_sel:[0,0] op_sel_hi:[1,0]":"=v"(d):"v"(a),"v"(b));return d;}
__device__ __forceinline__ v2f pk_fma_blo(v2f a, v2f b, v2f c){v2f d;asm("v_pk_fma_f32 %0,%1,%2,%3 op_sel:[0,0,0] op_sel_hi:[1,0,1]":"=v"(d):"v"(a),"v"(b),"v"(c));return d;}
__device__ __forceinline__ v2f pk_fma_bhi(v2f a, v2f b, v2f c){v2f d;asm("v_pk_fma_f32 %0,%1,%2,%3 op_sel:[0,1,0] op_sel_hi:[1,1,1]":"=v"(d):"v"(a),"v"(b),"v"(c));return d;}

__device__ __forceinline__ v2f XY(const float4& q){ v2f r = {q.x, q.y}; return r; }
__device__ __forceinline__ v2f ZW(const float4& q){ v2f r = {q.z, q.w}; return r; }

// One MPS site for 2 packed batches; lane owns output bond e.
// wc = lane's 16-float column: slots f*8+m, slot m holds w[d=e^m][f][e].
__device__ __forceinline__ v2f site_step(v2f v, const float* wc, v2f pp) {
    const float4 r0 = *(const float4*)(wc + 0);    // f0 m0..m3
    const float4 r1 = *(const float4*)(wc + 4);    // f0 m4..m7
    const float4 r2 = *(const float4*)(wc + 8);    // f1 m0..m3
    const float4 r3 = *(const float4*)(wc + 12);   // f1 m4..m7
    v2f t1; t1.x = dpp_q1(v.x);  t1.y = dpp_q1(v.y);   // v[e^1]
    v2f t2; t2.x = dpp_q2(v.x);  t2.y = dpp_q2(v.y);   // v[e^2]
    v2f t3; t3.x = dpp_q3(v.x);  t3.y = dpp_q3(v.y);   // v[e^3]
    v2f t7; t7.x = dpp_x7(v.x);  t7.y = dpp_x7(v.y);   // v[e^7]
    v2f t6; t6.x = dpp_q1(t7.x); t6.y = dpp_q1(t7.y);  // v[e^6]
    v2f t5; t5.x = dpp_q2(t7.x); t5.y = dpp_q2(t7.y);  // v[e^5]
    v2f t4; t4.x = dpp_q3(t7.x); t4.y = dpp_q3(t7.y);  // v[e^4]
    v2f a0 = pk_mul_blo(v,  XY(r0));          // m0 : w = r0.x
    a0 = pk_fma_bhi(t1, XY(r0), a0);          // m1 : w = r0.y
    a0 = pk_fma_blo(t2, ZW(r0), a0);          // m2 : w = r0.z
    a0 = pk_fma_bhi(t3, ZW(r0), a0);          // m3 : w = r0.w
    a0 = pk_fma_blo(t4, XY(r1), a0);          // m4
    a0 = pk_fma_bhi(t5, XY(r1), a0);          // m5
    a0 = pk_fma_blo(t6, ZW(r1), a0);          // m6
    a0 = pk_fma_bhi(t7, ZW(r1), a0);          // m7
    v2f a1 = pk_mul_blo(v,  XY(r2));
    a1 = pk_fma_bhi(t1, XY(r2), a1);
    a1 = pk_fma_blo(t2, ZW(r2), a1);
    a1 = pk_fma_bhi(t3, ZW(r2), a1);
    a1 = pk_fma_blo(t4, XY(r3), a1);
    a1 = pk_fma_bhi(t5, XY(r3), a1);
    a1 = pk_fma_blo(t6, ZW(r3), a1);
    a1 = pk_fma_bhi(t7, ZW(r3), a1);
    const v2f df = pk_sub(a1, a0);
    return pk_fma(pp, df, a0);                // (1-p)a0 + p a1, per packed batch
}

__global__ __launch_bounds__(256, 2) void mps_fused(
    const float* __restrict__ x,      // [B, N]
    const float* __restrict__ w0,     // [2, D]
    const float* __restrict__ Wl,     // [391, d, f, e]
    const float* __restrict__ wlab,   // [D, 2, D, O] = 1280 floats
    const float* __restrict__ Wr,     // [390, d, f, e]
    const float* __restrict__ wlast,  // [D, 2]
    float* __restrict__ out)          // [B, O]
{
    __shared__ float wb[2][2][16 * WSITE];  // [side][buf] 40.0 KB
    __shared__ float xb[2][2][16 * XPST];   // [side][buf]  8.5 KB (pair-interleaved)
    __shared__ float wl[1280];              // 5.1 KB
    __shared__ float vout[2][256];          // 2.0 KB        (~55.6 KB total)

    const int tid  = threadIdx.x;
    const int side = tid >> 7;              // waves 0-1: left, 2-3: right
    const int stid = tid & 127;
    const int w    = stid >> 6;             // wave within side 0..1
    const int lane = stid & 63;
    const int e    = lane & 7;              // owned bond index
    const int g    = lane >> 3;             // batch group 0..7
    const int pr   = w * 8 + g;             // pair-row 0..15
    const int bl0  = w * 16 + g;            // lane's two block-local batches
    const int bl1  = w * 16 + 8 + g;
    const int b0   = blockIdx.x * 32;       // 32 batches per block, grid 512

    for (int k = tid; k < 320; k += 256)
        *(float4*)&wl[k * 4] = *(const float4*)&wlab[k * 4];

    // ------- staging registers (T14: load early, write late) -------
    float4 wr[4];
    float  xr[4];

    auto stage_load = [&](int c, int nt) {
        const float* W = side == 0 ? Wl : Wr;
        #pragma unroll
        for (int r = 0; r < 4; ++r) {
            const int cid = stid + 128 * r;        // 0..511 = 16 sites x 32
            const int s   = cid >> 5;
            const int u   = cid & 31;
            if (s < nt) {
                const int row = side == 0 ? (c * 16 + s) : (389 - c * 16 - s);
                wr[r] = *(const float4*)(W + (size_t)row * 128 + u * 4);
            }
        }
        #pragma unroll
        for (int r = 0; r < 4; ++r) {
            const int cid = stid + 128 * r;        // 0..511 = 32 b x 16 s
            const int b   = cid >> 4;
            const int sx  = cid & 15;
            if (sx < nt) {
                const int col = side == 0 ? (1 + c * 16 + sx) : (782 - c * 16 - sx);
                xr[r] = x[(size_t)(b0 + b) * NSITES + col];
            }
        }
    };

    // scatter (r6-verified): left  W[d][f][e] -> s*160 + e*20 + f*8 + (e^d)
    //                        right W[d][f][e] -> s*160 + d*20 + f*8 + (d^e)
    // x: batch bl site sx -> pr(bl)*34 + sx*2 + half(bl)
    auto stage_write = [&](int bufi, int nt) {
        float* wdst = wb[side][bufi];
        float* xdst = xb[side][bufi];
        #pragma unroll
        for (int r = 0; r < 4; ++r) {
            const int cid = stid + 128 * r;
            const int s   = cid >> 5;
            const int u   = cid & 31;
            const int d   = u >> 2;
            const int f   = (u >> 1) & 1;
            const int e4  = (u & 1) * 4;
            if (s < nt) {
                float* dst = wdst + s * WSITE + f * 8;
                const float vals[4] = {wr[r].x, wr[r].y, wr[r].z, wr[r].w};
                #pragma unroll
                for (int k = 0; k < 4; ++k) {
                    const int ee = e4 + k;
                    if (side == 0)
                        dst[ee * CST + (ee ^ d)] = vals[k];
                    else
                        dst[d * CST + (d ^ ee)] = vals[k];
                }
            }
        }
        #pragma unroll
        for (int r = 0; r < 4; ++r) {
            const int cid  = stid + 128 * r;
            const int b    = cid >> 4;
            const int sx   = cid & 15;
            const int prw  = (b >> 4) * 8 + (b & 7);
            const int half = (b >> 3) & 1;
            if (sx < nt)
                xdst[prw * XPST + sx * 2 + half] = xr[r];
        }
    };

    // ------- boundary init: v[e] for batches bl0, bl1 -------
    v2f vv;
    if (side == 0) {
        const float p0 = x[(size_t)(b0 + bl0) * NSITES];
        const float p1 = x[(size_t)(b0 + bl1) * NSITES];
        vv.x = fmaf(1.0f - p0, w0[e], p0 * w0[DIM + e]);
        vv.y = fmaf(1.0f - p1, w0[e], p1 * w0[DIM + e]);
    } else {
        const float p0 = x[(size_t)(b0 + bl0) * NSITES + (NSITES - 1)];
        const float p1 = x[(size_t)(b0 + bl1) * NSITES + (NSITES - 1)];
        vv.x = fmaf(1.0f - p0, wlast[e * 2], p0 * wlast[e * 2 + 1]);
        vv.y = fmaf(1.0f - p1, wlast[e * 2], p1 * wlast[e * 2 + 1]);
    }

    const int nt_tail = side ? 6 : 7;

    stage_load(0, 16);
    stage_write(0, 16);
    int buf = 0;

    auto compute16 = [&](int bufi) {
        const float* wp = &wb[side][bufi][e * CST];
        const float* xp = &xb[side][bufi][pr * XPST];
        #pragma unroll
        for (int jh = 0; jh < 8; ++jh) {
            const float4 xq = *(const float4*)(xp + jh * 4);  // 2 sites x (pA,pB)
            vv = site_step(vv, wp + (2 * jh + 0) * WSITE, XY(xq));
            vv = site_step(vv, wp + (2 * jh + 1) * WSITE, ZW(xq));
        }
    };

    #pragma unroll 1
    for (int c = 0; c < 23; ++c) {            // chunks 0..22 (full)
        __syncthreads();                      // chunk c staged; buf^1 free
        stage_load(c + 1, 16);
        compute16(buf);
        __builtin_amdgcn_sched_barrier(0);    // keep LDS writes after compute
        stage_write(buf ^ 1, 16);
        buf ^= 1;
    }

    // chunk 23 (full) + prefetch tail chunk 24
    __syncthreads();
    stage_load(24, nt_tail);
    compute16(buf);
    __builtin_amdgcn_sched_barrier(0);
    stage_write(buf ^ 1, nt_tail);
    buf ^= 1;

    // tail chunk 24 (7 sites left / 6 sites right)
    __syncthreads();
    {
        const float* wp = &wb[side][buf][e * CST];
        const float* xp = &xb[side][buf][pr * XPST];
        for (int j = 0; j < nt_tail; ++j) {
            v2f pp; pp.x = xp[j * 2]; pp.y = xp[j * 2 + 1];
            vv = site_step(vv, wp + j * WSITE, pp);
        }
    }

    // ------- publish bond vectors and combine at the label site -------
    vout[side][bl0 * 8 + e] = vv.x;
    vout[side][bl1 * 8 + e] = vv.y;
    __syncthreads();

    for (int idx = tid; idx < 320; idx += 256) {   // 32 batches x 10 outputs
        const int b = idx / 10;
        const int o = idx - b * 10;
        const float p = x[(size_t)(b0 + b) * NSITES + LABEL];
        const float qq = 1.0f - p;
        const float* vl = &vout[0][b * 8];
        const float* rv = &vout[1][b * 8];
        float acc = 0.0f;
        #pragma unroll
        for (int d = 0; d < DIM; ++d) {
            const float vld = vl[d];
            #pragma unroll
            for (int ee = 0; ee < DIM; ++ee) {
                const float m = fmaf(qq, wl[((d * 2 + 0) * DIM + ee) * ODIM + o],
                                     p * wl[((d * 2 + 1) * DIM + ee) * ODIM + o]);
                acc = fmaf(vld * rv[ee], m, acc);
            }
        }
        out[(size_t)(b0 + b) * ODIM + o] = acc;
    }
}

extern "C" void kernel_launch(void* const* d_in, const int* in_sizes, int n_in,
                              void* d_out, int out_size, void* d_ws, size_t ws_size,
                              hipStream_t stream) {
    (void)in_sizes; (void)n_in; (void)d_ws; (void)ws_size; (void)out_size;
    const float* x     = (const float*)d_in[0];
    const float* w0    = (const float*)d_in[1];
    const float* Wl    = (const float*)d_in[2];
    const float* wlab  = (const float*)d_in[3];
    const float* Wr    = (const float*)d_in[4];
    const float* wlast = (const float*)d_in[5];

    mps_fused<<<512, 256, 0, stream>>>(x, w0, Wl, wlab, Wr, wlast, (float*)d_out);
}

// Round 7
// 157.886 us; speedup vs baseline: 1.2097x; 1.1524x over previous
//
#include <hip/hip_runtime.h>

// Round 12: r9 (best, 88 us) + explicit register prefetch of weights.
// Model fitted to r6-r11: SIMD busy = W x duty exactly; kernel time = the
// serial per-site wall of ONE wave (r9 540 cy, r10 755, r11 712). r9's wall:
// ~128 cy VALU + ~30 DS-issue + ~80 staging + ~300 EXPOSED ds_read latency
// (8 b128 consumed in-site). r10's 1-site-ahead register double-buffer got
// the best per-wave duty measured (33%) but at 1 wave/SIMD. This round:
// r9's verified geometry/layout/numerics (E=2 e-pair per lane, K=1,
// 16 batches/wave, 512 blocks x 256 thr, 2 blocks/CU, 2 waves/SIMD)
// with ONLY compute16 changed: weights for site j+1 ds_read into wg[2][8]
// while site j computes from registers (r10's verified site_step), and all
// 4 x-quads preloaded per chunk. Clean A/B vs the 88 us baseline.

#define NSITES 784
#define DIM    8
#define ODIM   10
#define LABEL  392
#define WSITE  144   // floats per staged site: 4 q-columns * 36
#define QST    36    // column stride: 32 + 4 pad -> column q at banks 4q..4q+3
#define XST    20    // xb row stride: 16 sites + 4 pad

typedef float v2f __attribute__((ext_vector_type(2)));

// quad_perm rotations (each 4-lane quad = one batch's 4 output-pair lanes)
__device__ __forceinline__ float dpp_q1(float s){float d;asm("v_mov_b32_dpp %0, %1 quad_perm:[1,0,3,2] row_mask:0xf bank_mask:0xf":"=v"(d):"v"(s));return d;}
__device__ __forceinline__ float dpp_q2(float s){float d;asm("v_mov_b32_dpp %0, %1 quad_perm:[2,3,0,1] row_mask:0xf bank_mask:0xf":"=v"(d):"v"(s));return d;}
__device__ __forceinline__ float dpp_q3(float s){float d;asm("v_mov_b32_dpp %0, %1 quad_perm:[3,2,1,0] row_mask:0xf bank_mask:0xf":"=v"(d):"v"(s));return d;}

__device__ __forceinline__ v2f pk_mul(v2f a, v2f b){v2f d;asm("v_pk_mul_f32 %0,%1,%2":"=v"(d):"v"(a),"v"(b));return d;}
__device__ __forceinline__ v2f pk_fma(v2f a, v2f b, v2f c){v2f d;asm("v_pk_fma_f32 %0,%1,%2,%3":"=v"(d):"v"(a),"v"(b),"v"(c));return d;}
// src0 half-swapped: lo result uses src0.hi, hi result uses src0.lo
__device__ __forceinline__ v2f pk_fma_s(v2f a, v2f b, v2f c){v2f d;asm("v_pk_fma_f32 %0,%1,%2,%3 op_sel:[1,0,0] op_sel_hi:[0,1,1]":"=v"(d):"v"(a),"v"(b),"v"(c));return d;}
// src0 broadcast lo / broadcast hi (for the per-site p blend)
__device__ __forceinline__ v2f pk_fma_blo(v2f a, v2f b, v2f c){v2f d;asm("v_pk_fma_f32 %0,%1,%2,%3 op_sel:[0,0,0] op_sel_hi:[0,1,1]":"=v"(d):"v"(a),"v"(b),"v"(c));return d;}
__device__ __forceinline__ v2f pk_fma_bhi(v2f a, v2f b, v2f c){v2f d;asm("v_pk_fma_f32 %0,%1,%2,%3 op_sel:[1,0,0] op_sel_hi:[1,1,1]":"=v"(d):"v"(a),"v"(b),"v"(c));return d;}
// a - b
__device__ __forceinline__ v2f pk_sub(v2f a, v2f b){v2f d;asm("v_pk_add_f32 %0,%1,%2 neg_lo:[0,1] neg_hi:[0,1]":"=v"(d):"v"(a),"v"(b));return d;}

__device__ __forceinline__ v2f XY(const float4& q){ v2f r = {q.x, q.y}; return r; }
__device__ __forceinline__ v2f ZW(const float4& q){ v2f r = {q.z, q.w}; return r; }

// One MPS site for one batch, output pair (2q,2q+1) per lane.
// Weights come from registers (r[0..7] = the lane's 32-float column).
// Verified numerically in rounds 9/10 (absmax 8.7e-19).
template <bool PHI>
__device__ __forceinline__ v2f site_step(v2f v, const float4 (&r)[8], v2f pp) {
    v2f d1; d1.x = dpp_q1(v.x); d1.y = dpp_q1(v.y);   // v[·^2] pairs
    v2f d2; d2.x = dpp_q2(v.x); d2.y = dpp_q2(v.y);   // v[·^4] pairs
    v2f d3; d3.x = dpp_q3(v.x); d3.y = dpp_q3(v.y);   // v[·^6] pairs
    v2f a0 = pk_mul (v,  XY(r[0]));
    a0 = pk_fma_s(v,  ZW(r[0]), a0);
    a0 = pk_fma  (d1, XY(r[1]), a0);
    a0 = pk_fma_s(d1, ZW(r[1]), a0);
    a0 = pk_fma  (d2, XY(r[2]), a0);
    a0 = pk_fma_s(d2, ZW(r[2]), a0);
    a0 = pk_fma  (d3, XY(r[3]), a0);
    a0 = pk_fma_s(d3, ZW(r[3]), a0);
    v2f a1 = pk_mul (v,  XY(r[4]));
    a1 = pk_fma_s(v,  ZW(r[4]), a1);
    a1 = pk_fma  (d1, XY(r[5]), a1);
    a1 = pk_fma_s(d1, ZW(r[5]), a1);
    a1 = pk_fma  (d2, XY(r[6]), a1);
    a1 = pk_fma_s(d2, ZW(r[6]), a1);
    a1 = pk_fma  (d3, XY(r[7]), a1);
    a1 = pk_fma_s(d3, ZW(r[7]), a1);
    const v2f df = pk_sub(a1, a0);
    return PHI ? pk_fma_bhi(pp, df, a0) : pk_fma_blo(pp, df, a0);
}

__global__ __launch_bounds__(256, 2) void mps_fused(
    const float* __restrict__ x,      // [B, N]
    const float* __restrict__ w0,     // [2, D]
    const float* __restrict__ Wl,     // [391, d, f, e]
    const float* __restrict__ wlab,   // [D, 2, D, O] = 1280 floats
    const float* __restrict__ Wr,     // [390, d, f, e]
    const float* __restrict__ wlast,  // [D, 2]
    float* __restrict__ out)          // [B, O]
{
    __shared__ float wb[2][2][16 * WSITE];  // [side][buf] 36.9 KB
    __shared__ float xb[2][2][32 * XST];    // [side][buf] 10.2 KB
    __shared__ float wl[1280];              // 5.1 KB
    __shared__ float vout[2][256];          // 2.0 KB          (~54 KB total)

    const int tid  = threadIdx.x;
    const int side = tid >> 7;              // waves 0-1: left, 2-3: right
    const int stid = tid & 127;
    const int w    = stid >> 6;             // wave within side 0..1
    const int lane = stid & 63;
    const int q    = lane & 3;              // output-pair index (e = 2q, 2q+1)
    const int grp  = lane >> 2;             // batch group 0..15
    const int bl   = w * 16 + grp;          // block-local batch 0..31
    const int b0   = blockIdx.x * 32;

    for (int k = tid; k < 320; k += 256)
        *(float4*)&wl[k * 4] = *(const float4*)&wlab[k * 4];

    // ------- staging registers (T14: load early, write late) -------
    float4 wr[4];
    float  xr[4];

    auto stage_load = [&](int c, int nt) {
        const float* W = side == 0 ? Wl : Wr;
        #pragma unroll
        for (int r = 0; r < 4; ++r) {
            const int cid = stid + 128 * r;        // 0..511 = 16 sites x 32
            const int s   = cid >> 5;
            const int u   = cid & 31;
            if (s < nt) {
                const int row = side == 0 ? (c * 16 + s) : (389 - c * 16 - s);
                wr[r] = *(const float4*)(W + (size_t)row * 128 + u * 4);
            }
        }
        #pragma unroll
        for (int r = 0; r < 4; ++r) {
            const int cid = stid + 128 * r;        // 0..511 = 32 b x 16 s
            const int b   = cid >> 4;
            const int sx  = cid & 15;
            if (sx < nt) {
                const int col = side == 0 ? (1 + c * 16 + sx) : (782 - c * 16 - sx);
                xr[r] = x[(size_t)(b0 + b) * NSITES + col];
            }
        }
    };

    // scatter (verified r9): left  W[d][f][e] -> [e>>1]*36 + (f*8+(e^d))*2 + (e&1)
    //                        right W[d][f][e] -> [d>>1]*36 + (f*8+(d^e))*2 + (d&1)
    auto stage_write = [&](int bufi, int nt) {
        float* wdst = wb[side][bufi];
        float* xdst = xb[side][bufi];
        #pragma unroll
        for (int r = 0; r < 4; ++r) {
            const int cid = stid + 128 * r;
            const int s   = cid >> 5;
            const int u   = cid & 31;
            const int d   = u >> 2;
            const int f   = (u >> 1) & 1;
            const int e4  = (u & 1) * 4;
            if (s < nt) {
                float* dst = wdst + s * WSITE;
                const float vals[4] = {wr[r].x, wr[r].y, wr[r].z, wr[r].w};
                #pragma unroll
                for (int k = 0; k < 4; ++k) {
                    const int e = e4 + k;
                    if (side == 0)
                        dst[(e >> 1) * QST + (f * 8 + (e ^ d)) * 2 + (e & 1)] = vals[k];
                    else
                        dst[(d >> 1) * QST + (f * 8 + (d ^ e)) * 2 + (d & 1)] = vals[k];
                }
            }
        }
        #pragma unroll
        for (int r = 0; r < 4; ++r) {
            const int cid = stid + 128 * r;
            const int b   = cid >> 4;
            const int sx  = cid & 15;
            if (sx < nt)
                xdst[b * XST + sx] = xr[r];
        }
    };

    // ------- boundary init: output pair (2q, 2q+1) for batch bl -------
    v2f vv;
    {
        const int e0 = 2 * q, e1 = 2 * q + 1;
        if (side == 0) {
            const float p = x[(size_t)(b0 + bl) * NSITES];
            vv.x = fmaf(1.0f - p, w0[e0], p * w0[DIM + e0]);
            vv.y = fmaf(1.0f - p, w0[e1], p * w0[DIM + e1]);
        } else {
            const float p = x[(size_t)(b0 + bl) * NSITES + (NSITES - 1)];
            vv.x = fmaf(1.0f - p, wlast[e0 * 2], p * wlast[e0 * 2 + 1]);
            vv.y = fmaf(1.0f - p, wlast[e1 * 2], p * wlast[e1 * 2 + 1]);
        }
    }

    const int nt_tail = side ? 6 : 7;

    stage_load(0, 16);
    stage_write(0, 16);
    int buf = 0;

    // 16 sites; weights register-double-buffered: ds_read site j+1's 8 b128
    // while computing site j from wg[j&1]. x quads all preloaded (their
    // latency hides behind wg[0]'s wait). Fully unrolled -> static indexing.
    auto compute16 = [&](int bufi) {
        const float* wp = &wb[side][bufi][q * QST];
        const float* xp = &xb[side][bufi][bl * XST];
        float4 xqa[4];
        #pragma unroll
        for (int i = 0; i < 4; ++i)
            xqa[i] = *(const float4*)(xp + i * 4);
        float4 wg[2][8];
        #pragma unroll
        for (int i = 0; i < 8; ++i)
            wg[0][i] = *(const float4*)(wp + i * 4);
        #pragma unroll
        for (int j = 0; j < 16; ++j) {
            if (j < 15) {
                #pragma unroll
                for (int i = 0; i < 8; ++i)
                    wg[(j + 1) & 1][i] = *(const float4*)(wp + (j + 1) * WSITE + i * 4);
            }
            const float4& xq = xqa[j >> 2];
            const v2f pp = (j & 2) ? ZW(xq) : XY(xq);
            if (j & 1) vv = site_step<true >(vv, wg[j & 1], pp);
            else       vv = site_step<false>(vv, wg[j & 1], pp);
        }
    };

    #pragma unroll 1
    for (int c = 0; c < 23; ++c) {            // chunks 0..22 (full)
        __syncthreads();                      // chunk c staged; buf^1 free
        stage_load(c + 1, 16);
        compute16(buf);
        __builtin_amdgcn_sched_barrier(0);    // keep LDS writes after compute
        stage_write(buf ^ 1, 16);
        buf ^= 1;
    }

    // chunk 23 (full) + prefetch tail chunk 24
    __syncthreads();
    stage_load(24, nt_tail);
    compute16(buf);
    __builtin_amdgcn_sched_barrier(0);
    stage_write(buf ^ 1, nt_tail);
    buf ^= 1;

    // tail chunk 24 (7 sites left / 6 sites right)
    __syncthreads();
    {
        const float* wp = &wb[side][buf][q * QST];
        const float* xp = &xb[side][buf][bl * XST];
        for (int j = 0; j < nt_tail; ++j) {
            float4 r[8];
            #pragma unroll
            for (int i = 0; i < 8; ++i)
                r[i] = *(const float4*)(wp + j * WSITE + i * 4);
            v2f pp; pp.x = xp[j]; pp.y = pp.x;
            vv = site_step<false>(vv, r, pp);
        }
    }

    // ------- publish bond vectors and combine at the label site -------
    *(v2f*)&vout[side][bl * 8 + 2 * q] = vv;
    __syncthreads();

    for (int idx = tid; idx < 320; idx += 256) {   // 32 batches x 10 outputs
        const int b = idx / 10;
        const int o = idx - b * 10;
        const float p = x[(size_t)(b0 + b) * NSITES + LABEL];
        const float qq = 1.0f - p;
        const float* vl = &vout[0][b * 8];
        const float* rv = &vout[1][b * 8];
        float acc = 0.0f;
        #pragma unroll
        for (int d = 0; d < DIM; ++d) {
            const float vld = vl[d];
            #pragma unroll
            for (int ee = 0; ee < DIM; ++ee) {
                const float m = fmaf(qq, wl[((d * 2 + 0) * DIM + ee) * ODIM + o],
                                     p * wl[((d * 2 + 1) * DIM + ee) * ODIM + o]);
                acc = fmaf(vld * rv[ee], m, acc);
            }
        }
        out[(size_t)(b0 + b) * ODIM + o] = acc;
    }
}

extern "C" void kernel_launch(void* const* d_in, const int* in_sizes, int n_in,
                              void* d_out, int out_size, void* d_ws, size_t ws_size,
                              hipStream_t stream) {
    (void)in_sizes; (void)n_in; (void)d_ws; (void)ws_size; (void)out_size;
    const float* x     = (const float*)d_in[0];
    const float* w0    = (const float*)d_in[1];
    const float* Wl    = (const float*)d_in[2];
    const float* wlab  = (const float*)d_in[3];
    const float* Wr    = (const float*)d_in[4];
    const float* wlast = (const float*)d_in[5];

    mps_fused<<<512, 256, 0, stream>>>(x, w0, Wl, wlab, Wr, wlast, (float*)d_out);
}